// Round 2
// baseline (1656.998 us; speedup 1.0000x reference)
//
#include <hip/hip_runtime.h>

typedef _Float16 f16;
typedef _Float16 half8 __attribute__((ext_vector_type(8)));
typedef _Float16 half4 __attribute__((ext_vector_type(4)));
typedef float floatx4 __attribute__((ext_vector_type(4)));
typedef float floatx16 __attribute__((ext_vector_type(16)));

#define MFMA16(A, B, C) __builtin_amdgcn_mfma_f32_16x16x32_f16((A), (B), (C), 0, 0, 0)
#define MFMA32(A, B, C) __builtin_amdgcn_mfma_f32_32x32x16_f16((A), (B), (C), 0, 0, 0)

// async global->LDS, 16B per lane; dst is wave-uniform base (HW adds lane*16)
#define GLDS16(src, dst)                                      \
  __builtin_amdgcn_global_load_lds(                           \
      (const __attribute__((address_space(1))) void*)(src),   \
      (__attribute__((address_space(3))) void*)(dst), 16, 0, 0)

// hardware transpose read: lane l receives column (l&15) (4 halves = rows 0..3)
// of the 4x16 f16 subtile at (lane_addr - (l&15)*8); use addr = base + l*8.
#define TR_READ(dstv, p)                                        \
  asm volatile("ds_read_b64_tr_b16 %0, %1"                      \
               : "=v"(dstv)                                     \
               : "v"((__attribute__((address_space(3))) f16*)(p)))

#define BARRIER_LGKM()                                        \
  do {                                                        \
    asm volatile("s_waitcnt lgkmcnt(0)" ::: "memory");        \
    __builtin_amdgcn_s_barrier();                             \
  } while (0)

// Problem constants: B=128 N=1024 E=512 K=512 DICT=256

// ---------------- K0: Mt[j][i] = sum_k Wq[k][i] * Wk[k][j]  (512x512, fp32 acc -> fp16) -----
__global__ __launch_bounds__(256) void k_gemm_M(const float* __restrict__ Wq,
                                                const float* __restrict__ Wk,
                                                f16* __restrict__ Mt) {
  __shared__ __align__(16) float qa[16][64];
  __shared__ __align__(16) float kbs[16][64];
  const int tid = threadIdx.x;
  const int i0 = (blockIdx.x & 7) * 64;
  const int j0 = (blockIdx.x >> 3) * 64;
  const int tx = tid & 15, ty = tid >> 4;
  float acc[4][4] = {};
  for (int k0 = 0; k0 < 512; k0 += 16) {
    __syncthreads();
    const int kr = tid >> 4;
    const int c4 = (tid & 15) * 4;
    *(float4*)&qa[kr][c4]  = *(const float4*)&Wq[(k0 + kr) * 512 + i0 + c4];
    *(float4*)&kbs[kr][c4] = *(const float4*)&Wk[(k0 + kr) * 512 + j0 + c4];
    __syncthreads();
#pragma unroll
    for (int kk = 0; kk < 16; kk++) {
      float a[4], b[4];
#pragma unroll
      for (int x = 0; x < 4; x++) a[x] = qa[kk][ty * 4 + x];
#pragma unroll
      for (int y = 0; y < 4; y++) b[y] = kbs[kk][tx * 4 + y];
#pragma unroll
      for (int x = 0; x < 4; x++)
#pragma unroll
        for (int y = 0; y < 4; y++) acc[x][y] += a[x] * b[y];
    }
  }
#pragma unroll
  for (int x = 0; x < 4; x++)
#pragma unroll
    for (int y = 0; y < 4; y++)
      Mt[(j0 + tx * 4 + y) * 512 + (i0 + ty * 4 + x)] = (f16)acc[x][y];
}

// ---------------- K1: emb_h[b,n,e] = fp16(tok_emb[tok[b,n], e]) --------------------------
__global__ __launch_bounds__(256) void k_gather(const int* __restrict__ tok,
                                                const float* __restrict__ temb,
                                                f16* __restrict__ embh) {
  const long g = (long)blockIdx.x * 256 + threadIdx.x;
  const long flat = g * 8;
  const int row = (int)(flat >> 9);
  const int e0 = (int)(flat & 511);
  const int t = tok[row];
  const float4 v0 = *(const float4*)&temb[t * 512 + e0];
  const float4 v1 = *(const float4*)&temb[t * 512 + e0 + 4];
  half8 h;
  h[0] = (f16)v0.x; h[1] = (f16)v0.y; h[2] = (f16)v0.z; h[3] = (f16)v0.w;
  h[4] = (f16)v1.x; h[5] = (f16)v1.y; h[6] = (f16)v1.z; h[7] = (f16)v1.w;
  *(half8*)&embh[flat] = h;
}

// ---------------- K3: T = emb_h[131072x512] @ M[512x512] -> fp16 (Mt is [n][k]) -----------
__global__ __launch_bounds__(256) void k_gemm_T(const f16* __restrict__ A,
                                                const f16* __restrict__ Bt,
                                                f16* __restrict__ T) {
  __shared__ __align__(16) f16 smem[17408];
  f16* As = smem;          // 128 rows x 40 halves
  f16* Bs = smem + 5120;   // 128 rows x 40 halves
  const int tid = threadIdx.x;
  const long m0 = (long)blockIdx.y * 128;
  const int n0 = blockIdx.x * 128;
  const int w = tid >> 6, lane = tid & 63, lq = lane & 15, quad = lane >> 4;
  const int wm = w >> 1, wn = w & 1;
  floatx4 acc[4][4] = {};
  const int sr = tid >> 1, shc = (tid & 1) * 16;
  for (int k0 = 0; k0 < 512; k0 += 32) {
    half8 a0 = *(const half8*)&A[(m0 + sr) * 512 + k0 + shc];
    half8 a1 = *(const half8*)&A[(m0 + sr) * 512 + k0 + shc + 8];
    half8 b0 = *(const half8*)&Bt[(long)(n0 + sr) * 512 + k0 + shc];
    half8 b1 = *(const half8*)&Bt[(long)(n0 + sr) * 512 + k0 + shc + 8];
    __syncthreads();
    *(half8*)&As[sr * 40 + shc] = a0;
    *(half8*)&As[sr * 40 + shc + 8] = a1;
    *(half8*)&Bs[sr * 40 + shc] = b0;
    *(half8*)&Bs[sr * 40 + shc + 8] = b1;
    __syncthreads();
    half8 af[4], bf[4];
#pragma unroll
    for (int mt = 0; mt < 4; mt++) af[mt] = *(half8*)&As[(wm * 64 + mt * 16 + lq) * 40 + quad * 8];
#pragma unroll
    for (int nt = 0; nt < 4; nt++) bf[nt] = *(half8*)&Bs[(wn * 64 + nt * 16 + lq) * 40 + quad * 8];
#pragma unroll
    for (int mt = 0; mt < 4; mt++)
#pragma unroll
      for (int nt = 0; nt < 4; nt++) acc[mt][nt] = MFMA16(af[mt], bf[nt], acc[mt][nt]);
  }
  __syncthreads();
  f16* Cp = smem;
#pragma unroll
  for (int mt = 0; mt < 4; mt++)
#pragma unroll
    for (int nt = 0; nt < 4; nt++)
#pragma unroll
      for (int rr = 0; rr < 4; rr++)
        Cp[(wm * 64 + mt * 16 + quad * 4 + rr) * 136 + wn * 64 + nt * 16 + lq] =
            (f16)acc[mt][nt][rr];
  __syncthreads();
  const int orow = tid >> 1, occ = (tid & 1) * 64;
#pragma unroll
  for (int i = 0; i < 8; i++) {
    half8 hv = *(half8*)&Cp[orow * 136 + occ + i * 8];
    *(half8*)&T[(m0 + orow) * 512 + n0 + occ + i * 8] = hv;
  }
}

// ---------------- K4 v5: causal flash attn, single K/V LDS tile + tr-reads ---------------
// 512 thr / 8 waves. Waves 0-3 (mh=w&1 key-half, nh=w>>1 q-half): QK via MFMA32 with
// Q fully register-resident (32x half8/lane, loaded once/tile). Waves 4-7: async
// global_load_lds staging of next 64-key K-tile (double buffered, drained at iter end).
// PV: all 8 waves (e-slice w*64) via MFMA16; V-frags = hardware transpose reads
// (ds_read_b64_tr_b16) of the SAME K-tile -> embt eliminated, working set 1 MB/batch
// (4 batches/XCD = 4 MB = L2-resident).
//
// K-tile LDS layout (64k x 512e, 4x16 f16 subtiles, perm'd so tr-read groups map to
// the MFMA16 B-frag): half_off(k,e) = es*1024 + ks*512 + perm8(kq)*64 + kr*16 + el
//   es=e>>4, el=e&15, ks=k>>5, kq=(k>>2)&7, kr=k&3, perm8(kq)=(kq>>1)|((kq&1)<<2)
__global__ __launch_bounds__(512, 2) void k_attn5(const f16* __restrict__ embh,
                                                  f16* tq_aff) {
  __shared__ __align__(16) f16 Kl[2][32768];   // 2 x 64KB K-tile buffers
  __shared__ __align__(16) f16 Pl[64 * 72];    // P [64q][64key] (+pad)
  __shared__ __align__(16) float wmax[4][32];
  __shared__ __align__(16) float wsum[4][32];
  __shared__ __align__(16) float alpha_s[64];
  __shared__ __align__(16) float l_s[64];

  const int tid = threadIdx.x;
  const int w = tid >> 6, lane = tid & 63;
  const int l31 = lane & 31, lh = lane >> 5;
  const int lq = lane & 15, quad = lane >> 4;

  // XCD swizzle: 8 consecutive slots per XCD; 4 co-resident batches per XCD (4 MB)
  const int bid = blockIdx.x;
  const int xcd = bid & 7, idx = bid >> 3;
  const int b = xcd * 16 + (idx >> 3);
  const int pair = idx & 7;
  const long bOff = (long)b * 1024 * 512;

  const int mh = w & 1, nh = w >> 1;        // q-wave roles (valid for w<4)
  const int qrow_l = nh * 32 + l31;         // q-row within 64-row tile

  // QK A-frag per-lane base (halves) inside a K-buffer
  const int kqi = l31 >> 2;
  const int p8i = (kqi >> 1) | ((kqi & 1) << 2);
  const int abase_off = mh * 512 + p8i * 64 + (l31 & 3) * 16 + lh * 8;
  // tr-read per-lane base (halves): wave's es-block + lane*4 (byte addr = base + l*8)
  const int trbase_off = (w * 4) * 1024 + lane * 4;

  for (int t = 0; t < 2; t++) {
    const int qb = t ? (15 - pair) : pair;
    const int q0 = qb * 64;
    __syncthreads();  // smem safe to restage (prev tile fully done)

    // ---- prologue: all waves stage K-tile kb=0 into Kl[0] (8 chunks each)
#pragma unroll
    for (int i = 0; i < 8; i++) {
      const int cbase = (w * 8 + i) * 64;
      const int c = cbase + lane;
      const int es = c >> 7, ks2 = (c >> 6) & 1, sp8 = (c >> 3) & 7,
                kr = (c >> 1) & 3, el8 = c & 1;
      const int skq = ((sp8 & 3) << 1) | (sp8 >> 2);
      const int k = ks2 * 32 + skq * 4 + kr;
      const int e = es * 16 + el8 * 8;
      GLDS16(&embh[bOff + (long)k * 512 + e], &Kl[0][cbase * 8]);
    }
    // ---- q-waves: Q tile -> registers (once per tile)
    half8 qreg[32];
    if (w < 4) {
      const f16* qsrc = &tq_aff[bOff + (long)(q0 + qrow_l) * 512 + lh * 8];
#pragma unroll
      for (int kc = 0; kc < 32; kc++) qreg[kc] = *(const half8*)&qsrc[kc * 16];
    }
    floatx4 Oa[4][4];
#pragma unroll
    for (int mt = 0; mt < 4; mt++)
#pragma unroll
      for (int nt = 0; nt < 4; nt++) Oa[mt][nt] = (floatx4)(0.f);
    float mrow = -1e30f, lrow = 0.f;
    const int qcol = q0 + qrow_l;

    asm volatile("s_waitcnt vmcnt(0)" ::: "memory");
    __builtin_amdgcn_s_barrier();
    int cur = 0;
    const int nkb = qb + 1;

    for (int kb = 0; kb < nkb; kb++) {
      float sv[16];
      if (w >= 4) {
        // ---- producer waves: stage kb+1 into other buffer (16 chunks each)
        if (kb < qb) {
          const int nxt = cur ^ 1;
#pragma unroll
          for (int i = 0; i < 16; i++) {
            const int cbase = ((w - 4) * 16 + i) * 64;
            const int c = cbase + lane;
            const int es = c >> 7, ks2 = (c >> 6) & 1, sp8 = (c >> 3) & 7,
                      kr = (c >> 1) & 3, el8 = c & 1;
            const int skq = ((sp8 & 3) << 1) | (sp8 >> 2);
            const int k = ks2 * 32 + skq * 4 + kr;
            const int e = es * 16 + el8 * 8;
            GLDS16(&embh[bOff + (long)((kb + 1) * 64 + k) * 512 + e],
                   &Kl[nxt][cbase * 8]);
          }
        }
      } else {
        // ---- QK: S^T quadrant [32key x 32q], A-frags from LDS, B from Q-regs
        const f16* ab = &Kl[cur][abase_off];
        floatx16 st = {};
#pragma unroll
        for (int kc8 = 0; kc8 < 4; kc8++) {
          half8 a[8];
#pragma unroll
          for (int i = 0; i < 8; i++) a[i] = *(const half8*)&ab[(kc8 * 8 + i) * 1024];
#pragma unroll
          for (int i = 0; i < 8; i++) st = MFMA32(a[i], qreg[kc8 * 8 + i], st);
        }
        float pm = -1e30f;
#pragma unroll
        for (int r = 0; r < 16; r++) {
          const int keyr = kb * 64 + mh * 32 + (r & 3) + 8 * (r >> 2) + 4 * lh;
          float s = st[r];
          if (keyr > qcol) s = -1e30f;
          sv[r] = s;
          pm = fmaxf(pm, s);
        }
        pm = fmaxf(pm, __shfl_xor(pm, 32, 64));
        if (lane < 32) wmax[w][lane] = pm;
      }
      BARRIER_LGKM();  // B1: wmax ready; prior-iter Pl readers done
      float al = 0.f;
      if (w < 4) {
        const float tmax = fmaxf(wmax[nh * 2][l31], wmax[nh * 2 + 1][l31]);
        const float mnew = fmaxf(mrow, tmax);
        al = exp2f((mrow - mnew) * 1.44269504f);
        float psum = 0.f;
        f16 ph[16];
#pragma unroll
        for (int r = 0; r < 16; r++) {
          const float p = exp2f((sv[r] - mnew) * 1.44269504f);
          psum += p;
          ph[r] = (f16)p;
        }
        psum += __shfl_xor(psum, 32, 64);
        if (lane < 32) wsum[w][lane] = psum;
        if (mh == 0 && lane < 32) alpha_s[nh * 32 + lane] = al;
#pragma unroll
        for (int grp = 0; grp < 4; grp++) {
          half4 hp = {ph[grp * 4 + 0], ph[grp * 4 + 1], ph[grp * 4 + 2], ph[grp * 4 + 3]};
          *(half4*)&Pl[(nh * 32 + l31) * 72 + mh * 32 + grp * 8 + lh * 4] = hp;
        }
        mrow = mnew;
      }
      BARRIER_LGKM();  // B2: Pl / wsum / alpha ready
      if (w < 4) lrow = lrow * al + wsum[nh * 2][l31] + wsum[nh * 2 + 1][l31];
      // ---- rescale O by alpha (all waves)
#pragma unroll
      for (int mt = 0; mt < 4; mt++) {
        const floatx4 av = *(const floatx4*)&alpha_s[mt * 16 + quad * 4];
#pragma unroll
        for (int nt = 0; nt < 4; nt++)
#pragma unroll
          for (int rr = 0; rr < 4; rr++) Oa[mt][nt][rr] *= av[rr];
      }
      // ---- PV: O[64q][64e/wave] += P @ V ; V-frags = tr-reads of the K-tile
#pragma unroll
      for (int ksv = 0; ksv < 2; ksv++) {
        f16* trp = &Kl[cur][trbase_off + ksv * 512];
        half4 t0[4], t1[4];
#pragma unroll
        for (int nt = 0; nt < 4; nt++) {
          TR_READ(t0[nt], trp + nt * 1024);        // k = quad*8 + 0..3
          TR_READ(t1[nt], trp + nt * 1024 + 256);  // k = quad*8 + 4..7
        }
        half8 ap[4];
#pragma unroll
        for (int mt = 0; mt < 4; mt++)
          ap[mt] = *(const half8*)&Pl[(mt * 16 + lq) * 72 + ksv * 32 + quad * 8];
        asm volatile("s_waitcnt lgkmcnt(0)" ::: "memory");
        __builtin_amdgcn_sched_barrier(0);
        half8 bv[4];
#pragma unroll
        for (int nt = 0; nt < 4; nt++)
          bv[nt] = __builtin_shufflevector(t0[nt], t1[nt], 0, 1, 2, 3, 4, 5, 6, 7);
#pragma unroll
        for (int mt = 0; mt < 4; mt++)
#pragma unroll
          for (int nt = 0; nt < 4; nt++) Oa[mt][nt] = MFMA16(ap[mt], bv[nt], Oa[mt][nt]);
      }
      if (w >= 4) asm volatile("s_waitcnt vmcnt(0)" ::: "memory");  // staged tile landed
      BARRIER_LGKM();  // B3: next buffer ready; Pl/K readers done
      cur ^= 1;
    }
    // ---- epilogue: divide by l, pack f16 via LDS (overlays Kl), coalesced write
    if (w < 4 && mh == 0 && lane < 32) l_s[nh * 32 + lane] = lrow;
    __syncthreads();
    f16* Ob = &Kl[0][0];  // [64][520]
#pragma unroll
    for (int mt = 0; mt < 4; mt++) {
      const floatx4 lv = *(const floatx4*)&l_s[mt * 16 + quad * 4];
#pragma unroll
      for (int nt = 0; nt < 4; nt++) {
        const int col = w * 64 + nt * 16 + lq;
#pragma unroll
        for (int rr = 0; rr < 4; rr++)
          Ob[(mt * 16 + quad * 4 + rr) * 520 + col] = (f16)(Oa[mt][nt][rr] / lv[rr]);
      }
    }
    __syncthreads();
    {
      const int row = tid >> 3, c0 = (tid & 7) * 64;
#pragma unroll
      for (int i = 0; i < 8; i++) {
        half8 v = *(half8*)&Ob[row * 520 + c0 + i * 8];
        *(half8*)&tq_aff[bOff + (long)(q0 + row) * 512 + c0 + i * 8] = v;
      }
    }
  }
}

// ---------------- K5: split-K output GEMM: partial[blk] = aff[:,chunk] @ Wl[:,chunk]^T ----
__global__ __launch_bounds__(256) void k_out_partial(const f16* __restrict__ aff,
                                                     const float* __restrict__ Wl,
                                                     float* __restrict__ part) {
  __shared__ __align__(16) f16 smem[15360];
  f16* As = smem;
  f16* Bs = smem + 5120;
  const int tid = threadIdx.x;
  const int w = tid >> 6, lane = tid & 63, lq = lane & 15, quad = lane >> 4;
  const int wm = w >> 1, wn = w & 1;
  const long kbase = (long)blockIdx.x * 1024;
  floatx4 acc[4][8] = {};
  const int rA = tid >> 1, hcA = (tid & 1) * 16;
  const int rB = tid >> 3, cB = (tid & 7) * 4;  // coalesced B-stage: 8 lanes x 16B per row
  for (int k0 = 0; k0 < 1024; k0 += 32) {
    const long kk = kbase + k0;
    half8 a0 = *(const half8*)&aff[(long)rA * 524288 + kk + hcA];
    half8 a1 = *(const half8*)&aff[(long)rA * 524288 + kk + hcA + 8];
    float4 bv[8];
#pragma unroll
    for (int pass = 0; pass < 8; pass++)
      bv[pass] = *(const float4*)&Wl[(long)(pass * 32 + rB) * 524288 + kk + cB];
    __syncthreads();
    *(half8*)&As[rA * 40 + hcA] = a0;
    *(half8*)&As[rA * 40 + hcA + 8] = a1;
#pragma unroll
    for (int pass = 0; pass < 8; pass++) {
      half4 hb = {(f16)bv[pass].x, (f16)bv[pass].y, (f16)bv[pass].z, (f16)bv[pass].w};
      *(half4*)&Bs[(pass * 32 + rB) * 40 + cB] = hb;
    }
    __syncthreads();
    half8 af[4], bf[8];
#pragma unroll
    for (int mt = 0; mt < 4; mt++) af[mt] = *(half8*)&As[(wm * 64 + mt * 16 + lq) * 40 + quad * 8];
#pragma unroll
    for (int nt = 0; nt < 8; nt++) bf[nt] = *(half8*)&Bs[(wn * 128 + nt * 16 + lq) * 40 + quad * 8];
#pragma unroll
    for (int mt = 0; mt < 4; mt++)
#pragma unroll
      for (int nt = 0; nt < 8; nt++) acc[mt][nt] = MFMA16(af[mt], bf[nt], acc[mt][nt]);
  }
  float* po = part + (long)blockIdx.x * 32768;
#pragma unroll
  for (int mt = 0; mt < 4; mt++)
#pragma unroll
    for (int nt = 0; nt < 8; nt++)
#pragma unroll
      for (int rr = 0; rr < 4; rr++)
        po[(wm * 64 + mt * 16 + quad * 4 + rr) * 256 + wn * 128 + nt * 16 + lq] =
            acc[mt][nt][rr];
}

// ---------------- K6: out = sum_p partial[p] + b_lin -------------------------------------
__global__ __launch_bounds__(256) void k_reduce(const float* __restrict__ part,
                                                const float* __restrict__ bl,
                                                float* __restrict__ out) {
  const int idx = blockIdx.x * 256 + threadIdx.x;
  float s = bl[idx & 255];
  for (int p = 0; p < 512; p++) s += part[(long)p * 32768 + idx];
  out[idx] = s;
}

extern "C" void kernel_launch(void* const* d_in, const int* in_sizes, int n_in,
                              void* d_out, int out_size, void* d_ws, size_t ws_size,
                              hipStream_t stream) {
  (void)in_sizes; (void)n_in; (void)out_size; (void)ws_size;
  const int* tok = (const int*)d_in[0];
  const float* temb = (const float*)d_in[1];
  const float* Wq = (const float*)d_in[2];
  const float* Wk = (const float*)d_in[3];
  // d_in[4] = Wv : computed-but-unused in the reference
  const float* Wl = (const float*)d_in[5];
  const float* bl = (const float*)d_in[6];
  float* out = (float*)d_out;
  char* ws = (char*)d_ws;

  f16* embh = (f16*)(ws);                    // 128 MB [B,N,E] fp16 (K and V)
  f16* Tq = (f16*)(ws + 268435456L);         // 128 MB [B*N,K] fp16; becomes aff in K4
  f16* Mt = (f16*)(ws + 402653184L);         // 512 KB [n][k] fp16
  float* part = (float*)(ws);                // 64 MB, overlays embh (dead after K4)

  hipLaunchKernelGGL(k_gemm_M, dim3(64), dim3(256), 0, stream, Wq, Wk, Mt);
  hipLaunchKernelGGL(k_gather, dim3(32768), dim3(256), 0, stream, tok, temb, embh);
  hipLaunchKernelGGL(k_gemm_T, dim3(4, 1024), dim3(256), 0, stream, embh, Mt, Tq);
  hipLaunchKernelGGL(k_attn5, dim3(1024), dim3(512), 0, stream, embh, Tq);
  hipLaunchKernelGGL(k_out_partial, dim3(512), dim3(256), 0, stream, Tq, Wl, part);
  hipLaunchKernelGGL(k_reduce, dim3(128), dim3(256), 0, stream, part, bl, out);
}